// Round 1
// baseline (253.819 us; speedup 1.0000x reference)
//
#include <hip/hip_runtime.h>
#include <hip/hip_bf16.h>
#include <stdint.h>

#define B_SZ   2048
#define DDATA  768
#define DD0    128
#define NSAE   128
#define DD     32
#define NJK    4096   // NSAE*DD
#define KA2    4352   // NJK + 128 (acts0) + 128 (gate)

typedef unsigned short u16;
typedef short bf16x8 __attribute__((ext_vector_type(8)));
typedef float f32x4  __attribute__((ext_vector_type(4)));

static __device__ __forceinline__ u16 f2bf(float f) {
  __hip_bfloat16 h = __float2bfloat16(f);
  return *reinterpret_cast<u16*>(&h);
}

// async global->LDS, 16B per lane; LDS dst must be wave-uniform base + lane*16
static __device__ __forceinline__ void gload16(const u16* g, u16* l) {
  __builtin_amdgcn_global_load_lds(
      (const __attribute__((address_space(1))) unsigned int*)g,
      (__attribute__((address_space(3))) unsigned int*)l,
      16, 0, 0);
}

// ---------------- prep: x -> bf16 ----------------
__global__ __launch_bounds__(256) void k_xcast(const float* __restrict__ x,
                                               u16* __restrict__ xb) {
  int i = blockIdx.x * 256 + threadIdx.x;          // one float4 per thread
  float4 v = ((const float4*)x)[i];
  ushort4 o;
  o.x = f2bf(v.x); o.y = f2bf(v.y); o.z = f2bf(v.z); o.w = f2bf(v.w);
  ((ushort4*)xb)[i] = o;
}

// ---------------- prep: W_enc1 [j,d,k] -> W1T [j*32+k, d] bf16 ----------------
__global__ __launch_bounds__(256) void k_t1(const float* __restrict__ We1,
                                            u16* __restrict__ W1T) {
  __shared__ float ts[64 * 33];                    // [d][k], pad to kill conflicts
  int db = blockIdx.x, j = blockIdx.y, t = threadIdx.x;
  const float* src = We1 + (size_t)j * 24576 + db * 2048;  // 64 d-rows x 32 k
#pragma unroll
  for (int i = 0; i < 8; ++i) {
    int e = t + i * 256;
    int d = e >> 5, k = e & 31;
    ts[d * 33 + k] = src[e];
  }
  __syncthreads();
#pragma unroll
  for (int i = 0; i < 8; ++i) {
    int e = t + i * 256;
    int k = e >> 6, d = e & 63;
    W1T[(size_t)(j * 32 + k) * DDATA + db * 64 + d] = f2bf(ts[d * 33 + k]);
  }
}

// ------- prep: build B2T [768, 4352] bf16 = [W_dec1 ; W_dec0 ; b_dec1]^T -------
__global__ __launch_bounds__(256) void k_t2(const float* __restrict__ Wd1,
                                            const float* __restrict__ Wd0,
                                            const float* __restrict__ bd1,
                                            u16* __restrict__ B2T) {
  __shared__ float ts[64 * 65];
  int rb = blockIdx.x, dbk = blockIdx.y, t = threadIdx.x;
  const float* src; int r0, base;
  if (rb < 64)      { src = Wd1; r0 = rb * 64;        base = 0;    }
  else if (rb < 66) { src = Wd0; r0 = (rb - 64) * 64; base = 4096; }
  else              { src = bd1; r0 = (rb - 66) * 64; base = 4224; }
  int d0 = dbk * 64;
#pragma unroll
  for (int i = 0; i < 16; ++i) {
    int e = t + i * 256;
    int ri = e >> 6, di = e & 63;
    ts[ri * 65 + di] = src[(size_t)(r0 + ri) * DDATA + d0 + di];
  }
  __syncthreads();
#pragma unroll
  for (int i = 0; i < 16; ++i) {
    int e = t + i * 256;
    int di = e >> 6, ri = e & 63;
    B2T[(size_t)(d0 + di) * KA2 + base + r0 + ri] = f2bf(ts[ri * 65 + di]);
  }
}

// -------- prep: c[j*32+k] = b_enc1[j,k] - sum_d b_dec1[j,d]*W_enc1[j,d,k] --------
__global__ __launch_bounds__(256) void k_cconst(const float* __restrict__ We1,
                                                const float* __restrict__ be1,
                                                const float* __restrict__ bd1,
                                                float* __restrict__ cv) {
  __shared__ float red[8][32];
  int j = blockIdx.x, t = threadIdx.x;
  int k = t & 31, g = t >> 5;
  float acc = 0.f;
  for (int d = g; d < DDATA; d += 8)
    acc += bd1[j * DDATA + d] * We1[(size_t)j * 24576 + d * 32 + k];
  red[g][k] = acc;
  __syncthreads();
  if (g == 0) {
    float s = 0.f;
#pragma unroll
    for (int q = 0; q < 8; ++q) s += red[q][k];
    cv[j * 32 + k] = be1[j * 32 + k] - s;
  }
}

// ---- gate/acts0: fp64-exact preact0 = (x-b_dec0)@W_enc0 + b_enc0; fill A2 cols ----
__global__ __launch_bounds__(256) void k_gate(const float* __restrict__ x,
                                              const float* __restrict__ We0,
                                              const float* __restrict__ be0,
                                              const float* __restrict__ bd0,
                                              u16* __restrict__ A2) {
  __shared__ float xs[8 * DDATA];     // 24 KB
  __shared__ double red[128 * 8];     // 8 KB
  int b0 = blockIdx.x * 8, t = threadIdx.x;
  for (int e = t; e < 8 * DDATA; e += 256) {
    int r = e / DDATA; int d = e - r * DDATA;
    xs[e] = x[(size_t)b0 * DDATA + e] - bd0[d];
  }
  __syncthreads();
  int j = t & 127, g = t >> 7;
  double acc[8];
  double binit = (double)be0[j];
#pragma unroll
  for (int r = 0; r < 8; ++r) acc[r] = g ? 0.0 : binit;
  for (int d = g * 384; d < g * 384 + 384; ++d) {
    double w = (double)We0[d * 128 + j];
#pragma unroll
    for (int r = 0; r < 8; ++r) acc[r] += (double)xs[r * DDATA + d] * w;
  }
  if (g == 1) {
#pragma unroll
    for (int r = 0; r < 8; ++r) red[j * 8 + r] = acc[r];
  }
  __syncthreads();
  if (g == 0) {
#pragma unroll
    for (int r = 0; r < 8; ++r) {
      double p = acc[r] + red[j * 8 + r];
      size_t row = (size_t)(b0 + r) * KA2;
      A2[row + NJK + j]       = f2bf(p > 0.0 ? (float)p : 0.f);      // acts0
      A2[row + NJK + 128 + j] = (p > 0.0) ? (u16)0x3F80 : (u16)0;    // gate (bf16 1/0)
    }
  }
}

// ---------------- GEMM: C = A[M,K] * B^T[N,K], bf16 MFMA 16x16x32 ----------------
// EPI=1: v = relu(v + c[gn]) * gate(b, gn>>5) -> bf16 into A2[:,0..4095]
// EPI=2: out[gm,gn] = v + b_dec0[gn]  (fp32)
template<int BM, int BN, int EPI>
__global__ __launch_bounds__(256) void k_gemm(const u16* __restrict__ A,
                                              const u16* __restrict__ Bm,
                                              int K,
                                              float* __restrict__ outF,
                                              const float* __restrict__ bias,
                                              u16* __restrict__ A2,
                                              const float* __restrict__ cvec) {
  constexpr int WM = BM / 32, WN = BN / 32;
  __shared__ __align__(16) u16 As[BM * 32];
  __shared__ __align__(16) u16 Bs[BN * 32];
  const int tid = threadIdx.x;
  const int bx = blockIdx.x, by = blockIdx.y;
  const u16* Ab = A  + (size_t)(by * BM) * K;
  const u16* Bb = Bm + (size_t)(bx * BN) * K;
  const int wave = tid >> 6, lane = tid & 63;
  const int wr = wave >> 1, wc = wave & 1;
  const int m0 = wr * (BM / 2), n0 = wc * (BN / 2);
  const int lm = lane & 15, kq = (lane >> 4) * 8;

  f32x4 acc[WM][WN];
  const f32x4 zero = {0.f, 0.f, 0.f, 0.f};
  for (int mi = 0; mi < WM; ++mi)
    for (int ni = 0; ni < WN; ++ni) acc[mi][ni] = zero;

  for (int k0 = 0; k0 < K; k0 += 32) {
#pragma unroll
    for (int i = 0; i < BM / 64; ++i) {
      int id = tid + 256 * i;
      gload16(Ab + (size_t)(id >> 2) * K + k0 + (id & 3) * 8, &As[id * 8]);
    }
#pragma unroll
    for (int i = 0; i < BN / 64; ++i) {
      int id = tid + 256 * i;
      gload16(Bb + (size_t)(id >> 2) * K + k0 + (id & 3) * 8, &Bs[id * 8]);
    }
    __syncthreads();
    bf16x8 af[WM], bfv[WN];
#pragma unroll
    for (int mi = 0; mi < WM; ++mi)
      af[mi] = *(const bf16x8*)&As[(m0 + mi * 16 + lm) * 32 + kq];
#pragma unroll
    for (int ni = 0; ni < WN; ++ni)
      bfv[ni] = *(const bf16x8*)&Bs[(n0 + ni * 16 + lm) * 32 + kq];
#pragma unroll
    for (int mi = 0; mi < WM; ++mi)
#pragma unroll
      for (int ni = 0; ni < WN; ++ni)
        acc[mi][ni] = __builtin_amdgcn_mfma_f32_16x16x32_bf16(af[mi], bfv[ni],
                                                              acc[mi][ni], 0, 0, 0);
    __syncthreads();
  }

  const int rb = (lane >> 4) * 4;
#pragma unroll
  for (int mi = 0; mi < WM; ++mi) {
#pragma unroll
    for (int ni = 0; ni < WN; ++ni) {
#pragma unroll
      for (int r = 0; r < 4; ++r) {
        int gm = by * BM + m0 + mi * 16 + rb + r;
        int gn = bx * BN + n0 + ni * 16 + lm;
        float v = acc[mi][ni][r];
        if (EPI == 1) {
          v += cvec[gn];
          v = v > 0.f ? v : 0.f;
          int jj = gn >> 5;
          u16 gbit = A2[(size_t)gm * KA2 + NJK + 128 + jj];
          v = gbit ? v : 0.f;
          A2[(size_t)gm * KA2 + gn] = f2bf(v);
        } else {
          outF[(size_t)gm * DDATA + gn] = v + bias[gn];
        }
      }
    }
  }
}

extern "C" void kernel_launch(void* const* d_in, const int* in_sizes, int n_in,
                              void* d_out, int out_size, void* d_ws, size_t ws_size,
                              hipStream_t stream) {
  const float* x   = (const float*)d_in[0];
  const float* We0 = (const float*)d_in[1];
  const float* be0 = (const float*)d_in[2];
  const float* Wd0 = (const float*)d_in[3];
  const float* bd0 = (const float*)d_in[4];
  const float* We1 = (const float*)d_in[5];
  const float* be1 = (const float*)d_in[6];
  const float* Wd1 = (const float*)d_in[7];
  const float* bd1 = (const float*)d_in[8];
  float* out = (float*)d_out;

  uint8_t* ws = (uint8_t*)d_ws;
  size_t off = 0;
  auto carve = [&](size_t bytes) {
    uint8_t* p = ws + off;
    off += (bytes + 255) & ~(size_t)255;
    return p;
  };
  u16*   A2  = (u16*)carve((size_t)B_SZ * KA2 * 2);     // [2048,4352] bf16
  u16*   xb  = (u16*)carve((size_t)B_SZ * DDATA * 2);   // [2048,768]  bf16
  u16*   W1T = (u16*)carve((size_t)NJK * DDATA * 2);    // [4096,768]  bf16 (B1^T)
  u16*   B2T = (u16*)carve((size_t)DDATA * KA2 * 2);    // [768,4352]  bf16 (B2^T)
  float* cv  = (float*)carve((size_t)NJK * 4);          // c[4096]

  k_xcast <<<1536, 256, 0, stream>>>(x, xb);
  k_t1    <<<dim3(12, 128), 256, 0, stream>>>(We1, W1T);
  k_t2    <<<dim3(68, 12),  256, 0, stream>>>(Wd1, Wd0, bd1, B2T);
  k_cconst<<<128, 256, 0, stream>>>(We1, be1, bd1, cv);
  k_gate  <<<256, 256, 0, stream>>>(x, We0, be0, bd0, A2);
  // GEMM1: pre/acts1 -> A2[:, 0..4095]   (M=2048, N=4096, K=768)
  k_gemm<128, 128, 1><<<dim3(32, 16), 256, 0, stream>>>(xb, W1T, DDATA,
                                                        nullptr, nullptr, A2, cv);
  // GEMM2: out = A2 @ B2 + b_dec0        (M=2048, N=768, K=4352)
  k_gemm<64, 128, 2><<<dim3(6, 32), 256, 0, stream>>>(A2, B2T, KA2,
                                                      out, bd0, A2, nullptr);
}

// Round 2
// 214.782 us; speedup vs baseline: 1.1818x; 1.1818x over previous
//
#include <hip/hip_runtime.h>
#include <hip/hip_bf16.h>
#include <stdint.h>

#define B_SZ   2048
#define DDATA  768
#define DD0    128
#define NSAE   128
#define DD     32
#define NJK    4096   // NSAE*DD
#define KA2    4352   // NJK + 128 (acts0) + 128 (gate)
#define SPLITK 4
#define KC2    1088   // KA2 / SPLITK (34 k-steps of 32)

typedef unsigned short u16;
typedef short bf16x8 __attribute__((ext_vector_type(8)));
typedef float f32x4  __attribute__((ext_vector_type(4)));

static __device__ __forceinline__ u16 f2bf(float f) {
  __hip_bfloat16 h = __float2bfloat16(f);
  return *reinterpret_cast<u16*>(&h);
}

// async global->LDS, 16B per lane; LDS dst must be wave-uniform base + lane*16
static __device__ __forceinline__ void gload16(const u16* g, u16* l) {
  __builtin_amdgcn_global_load_lds(
      (const __attribute__((address_space(1))) unsigned int*)g,
      (__attribute__((address_space(3))) unsigned int*)l,
      16, 0, 0);
}

// ---------------- prep: x -> bf16 ----------------
__global__ __launch_bounds__(256) void k_xcast(const float* __restrict__ x,
                                               u16* __restrict__ xb) {
  int i = blockIdx.x * 256 + threadIdx.x;          // one float4 per thread
  float4 v = ((const float4*)x)[i];
  ushort4 o;
  o.x = f2bf(v.x); o.y = f2bf(v.y); o.z = f2bf(v.z); o.w = f2bf(v.w);
  ((ushort4*)xb)[i] = o;
}

// ---------------- prep: W_enc1 [j,d,k] -> W1T [j*32+k, d] bf16 ----------------
__global__ __launch_bounds__(256) void k_t1(const float* __restrict__ We1,
                                            u16* __restrict__ W1T) {
  __shared__ float ts[64 * 33];                    // [d][k], pad to kill conflicts
  int db = blockIdx.x, j = blockIdx.y, t = threadIdx.x;
  const float* src = We1 + (size_t)j * 24576 + db * 2048;  // 64 d-rows x 32 k
#pragma unroll
  for (int i = 0; i < 8; ++i) {
    int e = t + i * 256;
    int d = e >> 5, k = e & 31;
    ts[d * 33 + k] = src[e];
  }
  __syncthreads();
#pragma unroll
  for (int i = 0; i < 8; ++i) {
    int e = t + i * 256;
    int k = e >> 6, d = e & 63;
    W1T[(size_t)(j * 32 + k) * DDATA + db * 64 + d] = f2bf(ts[d * 33 + k]);
  }
}

// ------- prep: build B2T [768, 4352] bf16 = [W_dec1 ; W_dec0 ; b_dec1]^T -------
__global__ __launch_bounds__(256) void k_t2(const float* __restrict__ Wd1,
                                            const float* __restrict__ Wd0,
                                            const float* __restrict__ bd1,
                                            u16* __restrict__ B2T) {
  __shared__ float ts[64 * 65];
  int rb = blockIdx.x, dbk = blockIdx.y, t = threadIdx.x;
  const float* src; int r0, base;
  if (rb < 64)      { src = Wd1; r0 = rb * 64;        base = 0;    }
  else if (rb < 66) { src = Wd0; r0 = (rb - 64) * 64; base = 4096; }
  else              { src = bd1; r0 = (rb - 66) * 64; base = 4224; }
  int d0 = dbk * 64;
#pragma unroll
  for (int i = 0; i < 16; ++i) {
    int e = t + i * 256;
    int ri = e >> 6, di = e & 63;
    ts[ri * 65 + di] = src[(size_t)(r0 + ri) * DDATA + d0 + di];
  }
  __syncthreads();
#pragma unroll
  for (int i = 0; i < 16; ++i) {
    int e = t + i * 256;
    int di = e >> 6, ri = e & 63;
    B2T[(size_t)(d0 + di) * KA2 + base + r0 + ri] = f2bf(ts[ri * 65 + di]);
  }
}

// -------- prep: c[j*32+k] = b_enc1[j,k] - sum_d b_dec1[j,d]*W_enc1[j,d,k] --------
__global__ __launch_bounds__(256) void k_cconst(const float* __restrict__ We1,
                                                const float* __restrict__ be1,
                                                const float* __restrict__ bd1,
                                                float* __restrict__ cv) {
  __shared__ float red[8][32];
  int j = blockIdx.x, t = threadIdx.x;
  int k = t & 31, g = t >> 5;
  float acc = 0.f;
  for (int d = g; d < DDATA; d += 8)
    acc += bd1[j * DDATA + d] * We1[(size_t)j * 24576 + d * 32 + k];
  red[g][k] = acc;
  __syncthreads();
  if (g == 0) {
    float s = 0.f;
#pragma unroll
    for (int q = 0; q < 8; ++q) s += red[q][k];
    cv[j * 32 + k] = be1[j * 32 + k] - s;
  }
}

// ---- gate/acts0: fp64-exact preact0 = (x-b_dec0)@W_enc0 + b_enc0; fill A2 cols ----
__global__ __launch_bounds__(256) void k_gate(const float* __restrict__ x,
                                              const float* __restrict__ We0,
                                              const float* __restrict__ be0,
                                              const float* __restrict__ bd0,
                                              u16* __restrict__ A2) {
  __shared__ float xs[8 * DDATA];     // 24 KB
  __shared__ double red[128 * 8];     // 8 KB
  int b0 = blockIdx.x * 8, t = threadIdx.x;
  for (int e = t; e < 8 * DDATA; e += 256) {
    int r = e / DDATA; int d = e - r * DDATA;
    xs[e] = x[(size_t)b0 * DDATA + e] - bd0[d];
  }
  __syncthreads();
  int j = t & 127, g = t >> 7;
  double acc[8];
  double binit = (double)be0[j];
#pragma unroll
  for (int r = 0; r < 8; ++r) acc[r] = g ? 0.0 : binit;
  for (int d = g * 384; d < g * 384 + 384; ++d) {
    double w = (double)We0[d * 128 + j];
#pragma unroll
    for (int r = 0; r < 8; ++r) acc[r] += (double)xs[r * DDATA + d] * w;
  }
  if (g == 1) {
#pragma unroll
    for (int r = 0; r < 8; ++r) red[j * 8 + r] = acc[r];
  }
  __syncthreads();
  if (g == 0) {
#pragma unroll
    for (int r = 0; r < 8; ++r) {
      double p = acc[r] + red[j * 8 + r];
      size_t row = (size_t)(b0 + r) * KA2;
      A2[row + NJK + j]       = f2bf(p > 0.0 ? (float)p : 0.f);      // acts0
      A2[row + NJK + 128 + j] = (p > 0.0) ? (u16)0x3F80 : (u16)0;    // gate (bf16 1/0)
    }
  }
}

// ---------------- GEMM: C = A[M,K] * B^T[N,K], bf16 MFMA 16x16x32 ----------------
// EPI=1: v = relu(v + c[gn]) * gate(b, gn>>5) -> bf16 into A2[:,0..4095]
// EPI=2: partial[z][gm][gn] = v  (split-K, fp32; reduced by k_reduce)
template<int BM, int BN, int EPI>
__global__ __launch_bounds__(256) void k_gemm(const u16* __restrict__ A,
                                              const u16* __restrict__ Bm,
                                              int K, int Kc,
                                              float* __restrict__ outF,
                                              u16* __restrict__ A2,
                                              const float* __restrict__ cvec) {
  constexpr int WM = BM / 32, WN = BN / 32;
  __shared__ __align__(16) u16 As[BM * 32];
  __shared__ __align__(16) u16 Bs[BN * 32];
  __shared__ u16 gate_s[BM * 4];    // EPI=1 only
  __shared__ float cv_s[BN];        // EPI=1 only
  const int tid = threadIdx.x;
  const int bx = blockIdx.x, by = blockIdx.y, bz = blockIdx.z;
  const int kbase = bz * Kc;
  const u16* Ab = A  + (size_t)(by * BM) * K;
  const u16* Bb = Bm + (size_t)(bx * BN) * K;
  const int wave = tid >> 6, lane = tid & 63;
  const int wr = wave >> 1, wc = wave & 1;
  const int m0 = wr * (BM / 2), n0 = wc * (BN / 2);
  const int lm = lane & 15, kq = (lane >> 4) * 8;

  f32x4 acc[WM][WN];
  const f32x4 zero = {0.f, 0.f, 0.f, 0.f};
  for (int mi = 0; mi < WM; ++mi)
    for (int ni = 0; ni < WN; ++ni) acc[mi][ni] = zero;

  for (int k0 = kbase; k0 < kbase + Kc; k0 += 32) {
#pragma unroll
    for (int i = 0; i < BM / 64; ++i) {
      int id = tid + 256 * i;
      gload16(Ab + (size_t)(id >> 2) * K + k0 + (id & 3) * 8, &As[id * 8]);
    }
#pragma unroll
    for (int i = 0; i < BN / 64; ++i) {
      int id = tid + 256 * i;
      gload16(Bb + (size_t)(id >> 2) * K + k0 + (id & 3) * 8, &Bs[id * 8]);
    }
    __syncthreads();
    bf16x8 af[WM], bfv[WN];
#pragma unroll
    for (int mi = 0; mi < WM; ++mi)
      af[mi] = *(const bf16x8*)&As[(m0 + mi * 16 + lm) * 32 + kq];
#pragma unroll
    for (int ni = 0; ni < WN; ++ni)
      bfv[ni] = *(const bf16x8*)&Bs[(n0 + ni * 16 + lm) * 32 + kq];
#pragma unroll
    for (int mi = 0; mi < WM; ++mi)
#pragma unroll
      for (int ni = 0; ni < WN; ++ni)
        acc[mi][ni] = __builtin_amdgcn_mfma_f32_16x16x32_bf16(af[mi], bfv[ni],
                                                              acc[mi][ni], 0, 0, 0);
    __syncthreads();
  }

  if (EPI == 1) {
    // preload this block's gate tile (BM rows x 4 experts) and cvec slice
    for (int e = tid; e < BM * 4; e += 256) {
      int r = e >> 2, q = e & 3;
      gate_s[e] = A2[(size_t)(by * BM + r) * KA2 + NJK + 128 + bx * 4 + q];
    }
    for (int e = tid; e < BN; e += 256) cv_s[e] = cvec[bx * BN + e];
    __syncthreads();
  }

  const int rb = (lane >> 4) * 4;
#pragma unroll
  for (int mi = 0; mi < WM; ++mi) {
#pragma unroll
    for (int ni = 0; ni < WN; ++ni) {
#pragma unroll
      for (int r = 0; r < 4; ++r) {
        int ml = m0 + mi * 16 + rb + r;
        int nl = n0 + ni * 16 + lm;
        int gm = by * BM + ml;
        int gn = bx * BN + nl;
        float v = acc[mi][ni][r];
        if (EPI == 1) {
          v += cv_s[nl];
          v = v > 0.f ? v : 0.f;
          u16 gbit = gate_s[ml * 4 + (nl >> 5)];
          v = gbit ? v : 0.f;
          A2[(size_t)gm * KA2 + gn] = f2bf(v);
        } else {
          outF[((size_t)bz * B_SZ + gm) * DDATA + gn] = v;
        }
      }
    }
  }
}

// ---------------- reduce split-K partials + bias ----------------
__global__ __launch_bounds__(256) void k_reduce(const float* __restrict__ part,
                                                const float* __restrict__ bias,
                                                float* __restrict__ out) {
  const int N4 = B_SZ * DDATA / 4;                 // 393216 float4s
  int i = blockIdx.x * 256 + threadIdx.x;
  const float4* p4 = (const float4*)part;
  float4 s = p4[i];
#pragma unroll
  for (int z = 1; z < SPLITK; ++z) {
    float4 t = p4[i + z * N4];
    s.x += t.x; s.y += t.y; s.z += t.z; s.w += t.w;
  }
  float4 b = ((const float4*)bias)[i % (DDATA / 4)];
  s.x += b.x; s.y += b.y; s.z += b.z; s.w += b.w;
  ((float4*)out)[i] = s;
}

extern "C" void kernel_launch(void* const* d_in, const int* in_sizes, int n_in,
                              void* d_out, int out_size, void* d_ws, size_t ws_size,
                              hipStream_t stream) {
  const float* x   = (const float*)d_in[0];
  const float* We0 = (const float*)d_in[1];
  const float* be0 = (const float*)d_in[2];
  const float* Wd0 = (const float*)d_in[3];
  const float* bd0 = (const float*)d_in[4];
  const float* We1 = (const float*)d_in[5];
  const float* be1 = (const float*)d_in[6];
  const float* Wd1 = (const float*)d_in[7];
  const float* bd1 = (const float*)d_in[8];
  float* out = (float*)d_out;

  uint8_t* ws = (uint8_t*)d_ws;
  size_t off = 0;
  auto carve = [&](size_t bytes) {
    uint8_t* p = ws + off;
    off += (bytes + 255) & ~(size_t)255;
    return p;
  };
  u16*   A2   = (u16*)carve((size_t)B_SZ * KA2 * 2);     // [2048,4352] bf16
  u16*   xb   = (u16*)carve((size_t)B_SZ * DDATA * 2);   // [2048,768]  bf16
  u16*   W1T  = (u16*)carve((size_t)NJK * DDATA * 2);    // [4096,768]  bf16 (B1^T)
  u16*   B2T  = (u16*)carve((size_t)DDATA * KA2 * 2);    // [768,4352]  bf16 (B2^T)
  float* cv   = (float*)carve((size_t)NJK * 4);          // c[4096]
  float* part = (float*)carve((size_t)SPLITK * B_SZ * DDATA * 4);  // 25.2 MB

  k_xcast <<<1536, 256, 0, stream>>>(x, xb);
  k_t1    <<<dim3(12, 128), 256, 0, stream>>>(We1, W1T);
  k_t2    <<<dim3(68, 12),  256, 0, stream>>>(Wd1, Wd0, bd1, B2T);
  k_cconst<<<128, 256, 0, stream>>>(We1, be1, bd1, cv);
  k_gate  <<<256, 256, 0, stream>>>(x, We0, be0, bd0, A2);
  // GEMM1: pre/acts1 -> A2[:, 0..4095]   (M=2048, N=4096, K=768)
  k_gemm<128, 128, 1><<<dim3(32, 16, 1), 256, 0, stream>>>(xb, W1T, DDATA, DDATA,
                                                           nullptr, A2, cv);
  // GEMM2 split-K: part[z] = A2 @ B2 over K-chunk z   (M=2048, N=768, K=4352)
  k_gemm<64, 128, 2><<<dim3(6, 32, SPLITK), 256, 0, stream>>>(A2, B2T, KA2, KC2,
                                                              part, nullptr, nullptr);
  // out = sum_z part[z] + b_dec0
  k_reduce<<<1536, 256, 0, stream>>>(part, bd0, out);
}

// Round 3
// 209.240 us; speedup vs baseline: 1.2131x; 1.0265x over previous
//
#include <hip/hip_runtime.h>
#include <hip/hip_bf16.h>
#include <stdint.h>

#define B_SZ   2048
#define DDATA  768
#define DD0    128
#define NSAE   128
#define DD     32
#define NJK    4096   // NSAE*DD
#define KA2    4352   // NJK + 128 (acts0) + 128 (gate)
#define SPLITK 4
#define KC2    1088   // KA2 / SPLITK (34 k-steps of 32)
#define GDCH   4      // gate d-split chunks
#define GDW    192    // DDATA / GDCH

typedef unsigned short u16;
typedef short bf16x8 __attribute__((ext_vector_type(8)));
typedef float f32x4  __attribute__((ext_vector_type(4)));

static __device__ __forceinline__ u16 f2bf(float f) {
  __hip_bfloat16 h = __float2bfloat16(f);
  return *reinterpret_cast<u16*>(&h);
}

// async global->LDS, 16B per lane; LDS dst must be wave-uniform base + lane*16
static __device__ __forceinline__ void gload16(const u16* g, u16* l) {
  __builtin_amdgcn_global_load_lds(
      (const __attribute__((address_space(1))) unsigned int*)g,
      (__attribute__((address_space(3))) unsigned int*)l,
      16, 0, 0);
}

// ---------------- prep: x -> bf16 ----------------
__global__ __launch_bounds__(256) void k_xcast(const float* __restrict__ x,
                                               u16* __restrict__ xb) {
  int i = blockIdx.x * 256 + threadIdx.x;          // one float4 per thread
  float4 v = ((const float4*)x)[i];
  ushort4 o;
  o.x = f2bf(v.x); o.y = f2bf(v.y); o.z = f2bf(v.z); o.w = f2bf(v.w);
  ((ushort4*)xb)[i] = o;
}

// ---------------- prep: W_enc1 [j,d,k] -> W1T [j*32+k, d] bf16 ----------------
__global__ __launch_bounds__(256) void k_t1(const float* __restrict__ We1,
                                            u16* __restrict__ W1T) {
  __shared__ float ts[64 * 33];                    // [d][k], pad to kill conflicts
  int db = blockIdx.x, j = blockIdx.y, t = threadIdx.x;
  const float* src = We1 + (size_t)j * 24576 + db * 2048;  // 64 d-rows x 32 k
#pragma unroll
  for (int i = 0; i < 8; ++i) {
    int e = t + i * 256;
    int d = e >> 5, k = e & 31;
    ts[d * 33 + k] = src[e];
  }
  __syncthreads();
#pragma unroll
  for (int i = 0; i < 8; ++i) {
    int e = t + i * 256;
    int k = e >> 6, d = e & 63;
    W1T[(size_t)(j * 32 + k) * DDATA + db * 64 + d] = f2bf(ts[d * 33 + k]);
  }
}

// ------- prep: build B2T [768, 4352] bf16 = [W_dec1 ; W_dec0 ; b_dec1]^T -------
__global__ __launch_bounds__(256) void k_t2(const float* __restrict__ Wd1,
                                            const float* __restrict__ Wd0,
                                            const float* __restrict__ bd1,
                                            u16* __restrict__ B2T) {
  __shared__ float ts[64 * 65];
  int rb = blockIdx.x, dbk = blockIdx.y, t = threadIdx.x;
  const float* src; int r0, base;
  if (rb < 64)      { src = Wd1; r0 = rb * 64;        base = 0;    }
  else if (rb < 66) { src = Wd0; r0 = (rb - 64) * 64; base = 4096; }
  else              { src = bd1; r0 = (rb - 66) * 64; base = 4224; }
  int d0 = dbk * 64;
#pragma unroll
  for (int i = 0; i < 16; ++i) {
    int e = t + i * 256;
    int ri = e >> 6, di = e & 63;
    ts[ri * 65 + di] = src[(size_t)(r0 + ri) * DDATA + d0 + di];
  }
  __syncthreads();
#pragma unroll
  for (int i = 0; i < 16; ++i) {
    int e = t + i * 256;
    int di = e >> 6, ri = e & 63;
    B2T[(size_t)(d0 + di) * KA2 + base + r0 + ri] = f2bf(ts[ri * 65 + di]);
  }
}

// -------- prep: c[j*32+k] = b_enc1[j,k] - sum_d b_dec1[j,d]*W_enc1[j,d,k] --------
__global__ __launch_bounds__(256) void k_cconst(const float* __restrict__ We1,
                                                const float* __restrict__ be1,
                                                const float* __restrict__ bd1,
                                                float* __restrict__ cv) {
  __shared__ float red[8][32];
  int j = blockIdx.x, t = threadIdx.x;
  int k = t & 31, g = t >> 5;
  float acc = 0.f;
  for (int d = g; d < DDATA; d += 8)
    acc += bd1[j * DDATA + d] * We1[(size_t)j * 24576 + d * 32 + k];
  red[g][k] = acc;
  __syncthreads();
  if (g == 0) {
    float s = 0.f;
#pragma unroll
    for (int q = 0; q < 8; ++q) s += red[q][k];
    cv[j * 32 + k] = be1[j * 32 + k] - s;
  }
}

// ---- gate partials: fp64 partial[z][b][j] over d-chunk z of (x-b_dec0)@W_enc0 ----
__global__ __launch_bounds__(256) void k_gatep(const float* __restrict__ x,
                                               const float* __restrict__ We0,
                                               const float* __restrict__ bd0,
                                               double* __restrict__ part) {
  __shared__ float xs[8 * GDW];       // 6 KB
  __shared__ double red[128 * 8];     // 8 KB
  const int b0 = blockIdx.x * 8, z = blockIdx.y, t = threadIdx.x;
  const int dbase = z * GDW;
  for (int e = t; e < 8 * GDW; e += 256) {
    int r = e / GDW, d = e - r * GDW;
    xs[e] = x[(size_t)(b0 + r) * DDATA + dbase + d] - bd0[dbase + d];
  }
  __syncthreads();
  const int j = t & 127, g = t >> 7;
  double acc[8];
#pragma unroll
  for (int r = 0; r < 8; ++r) acc[r] = 0.0;
  for (int dd = g * (GDW / 2); dd < (g + 1) * (GDW / 2); ++dd) {
    double w = (double)We0[(size_t)(dbase + dd) * 128 + j];
#pragma unroll
    for (int r = 0; r < 8; ++r) acc[r] += (double)xs[r * GDW + dd] * w;
  }
  if (g == 1) {
#pragma unroll
    for (int r = 0; r < 8; ++r) red[j * 8 + r] = acc[r];
  }
  __syncthreads();
  if (g == 0) {
#pragma unroll
    for (int r = 0; r < 8; ++r)
      part[((size_t)z * B_SZ + b0 + r) * 128 + j] = acc[r] + red[j * 8 + r];
  }
}

// ---- gate reduce: p = be0[j] + sum_z part[z][b][j]; write acts0/gate into A2 ----
__global__ __launch_bounds__(256) void k_gater(const double* __restrict__ part,
                                               const float* __restrict__ be0,
                                               u16* __restrict__ A2) {
  int i = blockIdx.x * 256 + threadIdx.x;          // 2048*128 threads
  int b = i >> 7, j = i & 127;
  double p = (double)be0[j];
#pragma unroll
  for (int z = 0; z < GDCH; ++z) p += part[((size_t)z * B_SZ + b) * 128 + j];
  size_t row = (size_t)b * KA2;
  A2[row + NJK + j]       = f2bf(p > 0.0 ? (float)p : 0.f);      // acts0
  A2[row + NJK + 128 + j] = (p > 0.0) ? (u16)0x3F80 : (u16)0;    // gate (bf16 1/0)
}

// ---------------- GEMM: C = A[M,K] * B^T[N,K], bf16 MFMA 16x16x32 ----------------
// EPI=1: v = relu(v + c[gn]) * gate(b, gn>>5) -> bf16 into A2[:,0..4095]
// EPI=2: partial[z][gm][gn] = v  (split-K, fp32; reduced by k_reduce)
template<int BM, int BN, int EPI>
__global__ __launch_bounds__(256) void k_gemm(const u16* __restrict__ A,
                                              const u16* __restrict__ Bm,
                                              int K, int Kc,
                                              float* __restrict__ outF,
                                              u16* __restrict__ A2,
                                              const float* __restrict__ cvec) {
  constexpr int WM = BM / 32, WN = BN / 32;
  __shared__ __align__(16) u16 As[BM * 32];
  __shared__ __align__(16) u16 Bs[BN * 32];
  __shared__ u16 gate_s[BM * 4];    // EPI=1 only
  __shared__ float cv_s[BN];        // EPI=1 only
  const int tid = threadIdx.x;
  const int bx = blockIdx.x, by = blockIdx.y, bz = blockIdx.z;
  const int kbase = bz * Kc;
  const u16* Ab = A  + (size_t)(by * BM) * K;
  const u16* Bb = Bm + (size_t)(bx * BN) * K;
  const int wave = tid >> 6, lane = tid & 63;
  const int wr = wave >> 1, wc = wave & 1;
  const int m0 = wr * (BM / 2), n0 = wc * (BN / 2);
  const int lm = lane & 15, kq = (lane >> 4) * 8;

  f32x4 acc[WM][WN];
  const f32x4 zero = {0.f, 0.f, 0.f, 0.f};
  for (int mi = 0; mi < WM; ++mi)
    for (int ni = 0; ni < WN; ++ni) acc[mi][ni] = zero;

  for (int k0 = kbase; k0 < kbase + Kc; k0 += 32) {
#pragma unroll
    for (int i = 0; i < BM / 64; ++i) {
      int id = tid + 256 * i;
      gload16(Ab + (size_t)(id >> 2) * K + k0 + (id & 3) * 8, &As[id * 8]);
    }
#pragma unroll
    for (int i = 0; i < BN / 64; ++i) {
      int id = tid + 256 * i;
      gload16(Bb + (size_t)(id >> 2) * K + k0 + (id & 3) * 8, &Bs[id * 8]);
    }
    __syncthreads();
    bf16x8 af[WM], bfv[WN];
#pragma unroll
    for (int mi = 0; mi < WM; ++mi)
      af[mi] = *(const bf16x8*)&As[(m0 + mi * 16 + lm) * 32 + kq];
#pragma unroll
    for (int ni = 0; ni < WN; ++ni)
      bfv[ni] = *(const bf16x8*)&Bs[(n0 + ni * 16 + lm) * 32 + kq];
#pragma unroll
    for (int mi = 0; mi < WM; ++mi)
#pragma unroll
      for (int ni = 0; ni < WN; ++ni)
        acc[mi][ni] = __builtin_amdgcn_mfma_f32_16x16x32_bf16(af[mi], bfv[ni],
                                                              acc[mi][ni], 0, 0, 0);
    __syncthreads();
  }

  if (EPI == 1) {
    // preload this block's gate tile (BM rows x 4 experts) and cvec slice
    for (int e = tid; e < BM * 4; e += 256) {
      int r = e >> 2, q = e & 3;
      gate_s[e] = A2[(size_t)(by * BM + r) * KA2 + NJK + 128 + bx * 4 + q];
    }
    for (int e = tid; e < BN; e += 256) cv_s[e] = cvec[bx * BN + e];
    __syncthreads();
  }

  const int rb = (lane >> 4) * 4;
#pragma unroll
  for (int mi = 0; mi < WM; ++mi) {
#pragma unroll
    for (int ni = 0; ni < WN; ++ni) {
#pragma unroll
      for (int r = 0; r < 4; ++r) {
        int ml = m0 + mi * 16 + rb + r;
        int nl = n0 + ni * 16 + lm;
        int gm = by * BM + ml;
        int gn = bx * BN + nl;
        float v = acc[mi][ni][r];
        if (EPI == 1) {
          v += cv_s[nl];
          v = v > 0.f ? v : 0.f;
          u16 gbit = gate_s[ml * 4 + (nl >> 5)];
          v = gbit ? v : 0.f;
          A2[(size_t)gm * KA2 + gn] = f2bf(v);
        } else {
          outF[((size_t)bz * B_SZ + gm) * DDATA + gn] = v;
        }
      }
    }
  }
}

// ---------------- reduce split-K partials + bias ----------------
__global__ __launch_bounds__(256) void k_reduce(const float* __restrict__ part,
                                                const float* __restrict__ bias,
                                                float* __restrict__ out) {
  const int N4 = B_SZ * DDATA / 4;                 // 393216 float4s
  int i = blockIdx.x * 256 + threadIdx.x;
  const float4* p4 = (const float4*)part;
  float4 s = p4[i];
#pragma unroll
  for (int z = 1; z < SPLITK; ++z) {
    float4 t = p4[i + z * N4];
    s.x += t.x; s.y += t.y; s.z += t.z; s.w += t.w;
  }
  float4 b = ((const float4*)bias)[i % (DDATA / 4)];
  s.x += b.x; s.y += b.y; s.z += b.z; s.w += b.w;
  ((float4*)out)[i] = s;
}

extern "C" void kernel_launch(void* const* d_in, const int* in_sizes, int n_in,
                              void* d_out, int out_size, void* d_ws, size_t ws_size,
                              hipStream_t stream) {
  const float* x   = (const float*)d_in[0];
  const float* We0 = (const float*)d_in[1];
  const float* be0 = (const float*)d_in[2];
  const float* Wd0 = (const float*)d_in[3];
  const float* bd0 = (const float*)d_in[4];
  const float* We1 = (const float*)d_in[5];
  const float* be1 = (const float*)d_in[6];
  const float* Wd1 = (const float*)d_in[7];
  const float* bd1 = (const float*)d_in[8];
  float* out = (float*)d_out;

  uint8_t* ws = (uint8_t*)d_ws;
  size_t off = 0;
  auto carve = [&](size_t bytes) {
    uint8_t* p = ws + off;
    off += (bytes + 255) & ~(size_t)255;
    return p;
  };
  u16*    A2   = (u16*)carve((size_t)B_SZ * KA2 * 2);     // [2048,4352] bf16
  u16*    xb   = (u16*)carve((size_t)B_SZ * DDATA * 2);   // [2048,768]  bf16
  u16*    W1T  = (u16*)carve((size_t)NJK * DDATA * 2);    // [4096,768]  bf16 (B1^T)
  u16*    B2T  = (u16*)carve((size_t)DDATA * KA2 * 2);    // [768,4352]  bf16 (B2^T)
  float*  cv   = (float*)carve((size_t)NJK * 4);          // c[4096]
  float*  part = (float*)carve((size_t)SPLITK * B_SZ * DDATA * 4);  // 25.2 MB
  double* gpart= (double*)carve((size_t)GDCH * B_SZ * 128 * 8);     // 8.4 MB

  k_xcast <<<1536, 256, 0, stream>>>(x, xb);
  k_t1    <<<dim3(12, 128), 256, 0, stream>>>(We1, W1T);
  k_t2    <<<dim3(68, 12),  256, 0, stream>>>(Wd1, Wd0, bd1, B2T);
  k_cconst<<<128, 256, 0, stream>>>(We1, be1, bd1, cv);
  // gate: fp64-exact preact0 in two stages (d-split for occupancy)
  k_gatep <<<dim3(256, GDCH), 256, 0, stream>>>(x, We0, bd0, gpart);
  k_gater <<<1024, 256, 0, stream>>>(gpart, be0, A2);
  // GEMM1: pre/acts1 -> A2[:, 0..4095]   (M=2048, N=4096, K=768)
  k_gemm<128, 128, 1><<<dim3(32, 16, 1), 256, 0, stream>>>(xb, W1T, DDATA, DDATA,
                                                           nullptr, A2, cv);
  // GEMM2 split-K: part[z] = A2 @ B2 over K-chunk z   (M=2048, N=768, K=4352)
  k_gemm<64, 128, 2><<<dim3(6, 32, SPLITK), 256, 0, stream>>>(A2, B2T, KA2, KC2,
                                                              part, nullptr, nullptr);
  // out = sum_z part[z] + b_dec0
  k_reduce<<<1536, 256, 0, stream>>>(part, bd0, out);
}

// Round 4
// 196.251 us; speedup vs baseline: 1.2933x; 1.0662x over previous
//
#include <hip/hip_runtime.h>
#include <hip/hip_bf16.h>
#include <stdint.h>

#define B_SZ   2048
#define DDATA  768
#define DD0    128
#define NSAE   128
#define DD     32
#define NJK    4096   // NSAE*DD
#define KA2    4352   // NJK + 128 (acts0) + 128 (gate)
#define SPLITK 4
#define KC2    1088   // KA2 / SPLITK
#define GZCH   8      // gate d-chunks
#define GZW    96     // DDATA / GZCH

typedef unsigned short u16;
typedef short bf16x8 __attribute__((ext_vector_type(8)));
typedef float f32x4  __attribute__((ext_vector_type(4)));

static __device__ __forceinline__ u16 f2bf(float f) {
  __hip_bfloat16 h = __float2bfloat16(f);
  return *reinterpret_cast<u16*>(&h);
}

static __device__ __forceinline__ void gload16(const u16* g, u16* l) {
  __builtin_amdgcn_global_load_lds(
      (const __attribute__((address_space(1))) unsigned int*)g,
      (__attribute__((address_space(3))) unsigned int*)l,
      16, 0, 0);
}

// ---------------- init: cv = b_enc1, cnt = 0 ----------------
__global__ __launch_bounds__(256) void k_init(const float* __restrict__ be1,
                                              float* __restrict__ cv,
                                              unsigned int* __restrict__ cnt) {
  int i = blockIdx.x * 256 + threadIdx.x;
  if (i < NJK) cv[i] = be1[i];
  if (i == 0) *cnt = 0u;
}

// ---------------- prep: x -> bf16 ----------------
__global__ __launch_bounds__(256) void k_xcast(const float* __restrict__ x,
                                               u16* __restrict__ xb) {
  int i = blockIdx.x * 256 + threadIdx.x;
  float4 v = ((const float4*)x)[i];
  ushort4 o;
  o.x = f2bf(v.x); o.y = f2bf(v.y); o.z = f2bf(v.z); o.w = f2bf(v.w);
  ((ushort4*)xb)[i] = o;
}

// ---- prep fused: W_enc1 transpose -> W1T bf16  AND  cv -= b_dec1[j,:]@W_enc1[j] ----
__global__ __launch_bounds__(256) void k_t1c(const float* __restrict__ We1,
                                             const float* __restrict__ bd1,
                                             u16* __restrict__ W1T,
                                             float* __restrict__ cv) {
  __shared__ float ts[64 * 33];
  __shared__ float bds[64];
  __shared__ float red[8][32];
  int db = blockIdx.x, j = blockIdx.y, t = threadIdx.x;
  const float* src = We1 + (size_t)j * 24576 + db * 2048;   // 64 d x 32 k slab
#pragma unroll
  for (int i = 0; i < 8; ++i) {
    int e = t + i * 256;
    ts[(e >> 5) * 33 + (e & 31)] = src[e];
  }
  if (t < 64) bds[t] = bd1[(size_t)j * DDATA + db * 64 + t];
  __syncthreads();
#pragma unroll
  for (int i = 0; i < 8; ++i) {
    int e = t + i * 256;
    int k = e >> 6, d = e & 63;
    W1T[(size_t)(j * 32 + k) * DDATA + db * 64 + d] = f2bf(ts[d * 33 + k]);
  }
  int k = t & 31, g = t >> 5;
  float acc = 0.f;
#pragma unroll
  for (int d = g; d < 64; d += 8) acc += ts[d * 33 + k] * bds[d];
  red[g][k] = acc;
  __syncthreads();
  if (g == 0) {
    float s = 0.f;
#pragma unroll
    for (int q = 0; q < 8; ++q) s += red[q][k];
    atomicAdd(&cv[j * 32 + k], -s);
  }
}

// ------- prep: build B2T [768, 4352] bf16 = [W_dec1 ; W_dec0 ; b_dec1]^T -------
__global__ __launch_bounds__(256) void k_t2(const float* __restrict__ Wd1,
                                            const float* __restrict__ Wd0,
                                            const float* __restrict__ bd1,
                                            u16* __restrict__ B2T) {
  __shared__ float ts[64 * 65];
  int rb = blockIdx.x, dbk = blockIdx.y, t = threadIdx.x;
  const float* src; int r0, base;
  if (rb < 64)      { src = Wd1; r0 = rb * 64;        base = 0;    }
  else if (rb < 66) { src = Wd0; r0 = (rb - 64) * 64; base = 4096; }
  else              { src = bd1; r0 = (rb - 66) * 64; base = 4224; }
  int d0 = dbk * 64;
#pragma unroll
  for (int i = 0; i < 16; ++i) {
    int e = t + i * 256;
    int ri = e >> 6, di = e & 63;
    ts[ri * 65 + di] = src[(size_t)(r0 + ri) * DDATA + d0 + di];
  }
  __syncthreads();
#pragma unroll
  for (int i = 0; i < 16; ++i) {
    int e = t + i * 256;
    int di = e >> 6, ri = e & 63;
    B2T[(size_t)(d0 + di) * KA2 + base + r0 + ri] = f2bf(ts[ri * 65 + di]);
  }
}

// ---- gate pass: fp32 partials p and S=sum|x||w| over d-chunk z, register-tiled ----
__global__ __launch_bounds__(256) void k_gatep3(const float* __restrict__ x,
                                                const float* __restrict__ We0,
                                                const float* __restrict__ bd0,
                                                float* __restrict__ pp,
                                                float* __restrict__ ps) {
  __shared__ float xs[32 * GZW];           // 12 KB
  const int b0 = blockIdx.x * 32, z = blockIdx.y, t = threadIdx.x;
  const int dbase = z * GZW;
#pragma unroll
  for (int i = 0; i < 12; ++i) {
    int e = t + i * 256;                   // 0..3071
    int r = e / GZW, d = e - r * GZW;
    xs[e] = x[(size_t)(b0 + r) * DDATA + dbase + d] - bd0[dbase + d];
  }
  __syncthreads();
  const int jp = t & 63, rg = t >> 6;      // wave-uniform rg
  const int j0 = jp * 2;
  float ap[8][2], as[8][2];
#pragma unroll
  for (int r = 0; r < 8; ++r) { ap[r][0]=ap[r][1]=as[r][0]=as[r][1]=0.f; }
  for (int d = 0; d < GZW; d += 4) {
    float4 xv[8];
#pragma unroll
    for (int r = 0; r < 8; ++r)
      xv[r] = *(const float4*)&xs[(rg * 8 + r) * GZW + d];  // wave-uniform b128
#pragma unroll
    for (int dd = 0; dd < 4; ++dd) {
      float2 w2 = *(const float2*)&We0[(size_t)(dbase + d + dd) * 128 + j0];
      float aw0 = fabsf(w2.x), aw1 = fabsf(w2.y);
#pragma unroll
      for (int r = 0; r < 8; ++r) {
        float xr  = ((const float*)&xv[r])[dd];
        float axr = fabsf(xr);
        ap[r][0] += xr * w2.x;   ap[r][1] += xr * w2.y;
        as[r][0] += axr * aw0;   as[r][1] += axr * aw1;
      }
    }
  }
#pragma unroll
  for (int r = 0; r < 8; ++r) {
    size_t o = ((size_t)z * B_SZ + b0 + rg * 8 + r) * 128 + j0;
    *(float2*)&pp[o] = make_float2(ap[r][0], ap[r][1]);
    *(float2*)&ps[o] = make_float2(as[r][0], as[r][1]);
  }
}

// ---- gate reduce: combine chunks, write acts0/gate, flag uncertain signs ----
__global__ __launch_bounds__(256) void k_gater2(const float* __restrict__ pp,
                                                const float* __restrict__ ps,
                                                const float* __restrict__ be0,
                                                u16* __restrict__ A2,
                                                unsigned int* __restrict__ cnt,
                                                unsigned int* __restrict__ list) {
  int i = blockIdx.x * 256 + threadIdx.x;  // 262144
  int b = i >> 7, j = i & 127;
  float p = be0[j], S = 0.f;
#pragma unroll
  for (int z = 0; z < GZCH; ++z) {
    size_t o = ((size_t)z * B_SZ + b) * 128 + j;
    p += pp[o]; S += ps[o];
  }
  size_t row = (size_t)b * KA2;
  A2[row + NJK + j]       = f2bf(p > 0.f ? p : 0.f);
  A2[row + NJK + 128 + j] = (p > 0.f) ? (u16)0x3F80 : (u16)0;
  if (fabsf(p) <= 1e-4f * S) {             // fp32 sign uncertain -> exact fix-up
    unsigned int idx = atomicAdd(cnt, 1u);
    list[idx] = (unsigned int)i;
  }
}

// ---- exact fp64 fix-up for flagged (b,j) ----
__global__ __launch_bounds__(256) void k_fix(const unsigned int* __restrict__ cnt,
                                             const unsigned int* __restrict__ list,
                                             const float* __restrict__ x,
                                             const float* __restrict__ We0,
                                             const float* __restrict__ be0,
                                             const float* __restrict__ bd0,
                                             u16* __restrict__ A2) {
  const int wid = blockIdx.x * 4 + (threadIdx.x >> 6);   // 0..383
  const int lane = threadIdx.x & 63;
  const unsigned int n = *cnt;
  for (unsigned int e = wid; e < n; e += 384) {
    unsigned int i = list[e];
    int b = (int)(i >> 7), j = (int)(i & 127);
    double acc = 0.0;
#pragma unroll
    for (int tt = 0; tt < 12; ++tt) {
      int d = lane + tt * 64;
      acc += (double)(x[(size_t)b * DDATA + d] - bd0[d]) *
             (double)We0[(size_t)d * 128 + j];
    }
#pragma unroll
    for (int s = 32; s; s >>= 1) acc += __shfl_xor(acc, s, 64);
    if (lane == 0) {
      double p = acc + (double)be0[j];
      size_t row = (size_t)b * KA2;
      A2[row + NJK + j]       = f2bf(p > 0.0 ? (float)p : 0.f);
      A2[row + NJK + 128 + j] = (p > 0.0) ? (u16)0x3F80 : (u16)0;
    }
  }
}

// ---------------- GEMM: C = A[M,K] * B^T[N,K], bf16 MFMA 16x16x32 ----------------
template<int BM, int BN, int EPI>
__global__ __launch_bounds__(256) void k_gemm(const u16* __restrict__ A,
                                              const u16* __restrict__ Bm,
                                              int K, int Kc,
                                              float* __restrict__ outF,
                                              u16* __restrict__ A2,
                                              const float* __restrict__ cvec) {
  constexpr int WM = BM / 32, WN = BN / 32;
  __shared__ __align__(16) u16 As[BM * 32];
  __shared__ __align__(16) u16 Bs[BN * 32];
  __shared__ u16 gate_s[BM * 4];
  __shared__ float cv_s[BN];
  const int tid = threadIdx.x;
  const int bx = blockIdx.x, by = blockIdx.y, bz = blockIdx.z;
  const int kbase = bz * Kc;
  const u16* Ab = A  + (size_t)(by * BM) * K;
  const u16* Bb = Bm + (size_t)(bx * BN) * K;
  const int wave = tid >> 6, lane = tid & 63;
  const int wr = wave >> 1, wc = wave & 1;
  const int m0 = wr * (BM / 2), n0 = wc * (BN / 2);
  const int lm = lane & 15, kq = (lane >> 4) * 8;

  f32x4 acc[WM][WN];
  const f32x4 zero = {0.f, 0.f, 0.f, 0.f};
  for (int mi = 0; mi < WM; ++mi)
    for (int ni = 0; ni < WN; ++ni) acc[mi][ni] = zero;

  for (int k0 = kbase; k0 < kbase + Kc; k0 += 32) {
#pragma unroll
    for (int i = 0; i < BM / 64; ++i) {
      int id = tid + 256 * i;
      gload16(Ab + (size_t)(id >> 2) * K + k0 + (id & 3) * 8, &As[id * 8]);
    }
#pragma unroll
    for (int i = 0; i < BN / 64; ++i) {
      int id = tid + 256 * i;
      gload16(Bb + (size_t)(id >> 2) * K + k0 + (id & 3) * 8, &Bs[id * 8]);
    }
    __syncthreads();
    bf16x8 af[WM], bfv[WN];
#pragma unroll
    for (int mi = 0; mi < WM; ++mi)
      af[mi] = *(const bf16x8*)&As[(m0 + mi * 16 + lm) * 32 + kq];
#pragma unroll
    for (int ni = 0; ni < WN; ++ni)
      bfv[ni] = *(const bf16x8*)&Bs[(n0 + ni * 16 + lm) * 32 + kq];
#pragma unroll
    for (int mi = 0; mi < WM; ++mi)
#pragma unroll
      for (int ni = 0; ni < WN; ++ni)
        acc[mi][ni] = __builtin_amdgcn_mfma_f32_16x16x32_bf16(af[mi], bfv[ni],
                                                              acc[mi][ni], 0, 0, 0);
    __syncthreads();
  }

  if (EPI == 1) {
    for (int e = tid; e < BM * 4; e += 256) {
      int r = e >> 2, q = e & 3;
      gate_s[e] = A2[(size_t)(by * BM + r) * KA2 + NJK + 128 + bx * 4 + q];
    }
    for (int e = tid; e < BN; e += 256) cv_s[e] = cvec[bx * BN + e];
    __syncthreads();
  }

  const int rb = (lane >> 4) * 4;
#pragma unroll
  for (int mi = 0; mi < WM; ++mi) {
#pragma unroll
    for (int ni = 0; ni < WN; ++ni) {
#pragma unroll
      for (int r = 0; r < 4; ++r) {
        int ml = m0 + mi * 16 + rb + r;
        int nl = n0 + ni * 16 + lm;
        int gm = by * BM + ml;
        int gn = bx * BN + nl;
        float v = acc[mi][ni][r];
        if (EPI == 1) {
          v += cv_s[nl];
          v = v > 0.f ? v : 0.f;
          u16 gbit = gate_s[ml * 4 + (nl >> 5)];
          v = gbit ? v : 0.f;
          A2[(size_t)gm * KA2 + gn] = f2bf(v);
        } else {
          outF[((size_t)bz * B_SZ + gm) * DDATA + gn] = v;
        }
      }
    }
  }
}

// ---------------- reduce split-K partials + bias ----------------
__global__ __launch_bounds__(256) void k_reduce(const float* __restrict__ part,
                                                const float* __restrict__ bias,
                                                float* __restrict__ out) {
  const int N4 = B_SZ * DDATA / 4;
  int i = blockIdx.x * 256 + threadIdx.x;
  const float4* p4 = (const float4*)part;
  float4 s = p4[i];
#pragma unroll
  for (int z = 1; z < SPLITK; ++z) {
    float4 t = p4[i + z * N4];
    s.x += t.x; s.y += t.y; s.z += t.z; s.w += t.w;
  }
  float4 b = ((const float4*)bias)[i % (DDATA / 4)];
  s.x += b.x; s.y += b.y; s.z += b.z; s.w += b.w;
  ((float4*)out)[i] = s;
}

extern "C" void kernel_launch(void* const* d_in, const int* in_sizes, int n_in,
                              void* d_out, int out_size, void* d_ws, size_t ws_size,
                              hipStream_t stream) {
  const float* x   = (const float*)d_in[0];
  const float* We0 = (const float*)d_in[1];
  const float* be0 = (const float*)d_in[2];
  const float* Wd0 = (const float*)d_in[3];
  const float* bd0 = (const float*)d_in[4];
  const float* We1 = (const float*)d_in[5];
  const float* be1 = (const float*)d_in[6];
  const float* Wd1 = (const float*)d_in[7];
  const float* bd1 = (const float*)d_in[8];
  float* out = (float*)d_out;

  uint8_t* ws = (uint8_t*)d_ws;
  size_t off = 0;
  auto carve = [&](size_t bytes) {
    uint8_t* p = ws + off;
    off += (bytes + 255) & ~(size_t)255;
    return p;
  };
  u16*    A2   = (u16*)carve((size_t)B_SZ * KA2 * 2);
  u16*    xb   = (u16*)carve((size_t)B_SZ * DDATA * 2);
  u16*    W1T  = (u16*)carve((size_t)NJK * DDATA * 2);
  u16*    B2T  = (u16*)carve((size_t)DDATA * KA2 * 2);
  float*  cv   = (float*)carve((size_t)NJK * 4);
  float*  part = (float*)carve((size_t)SPLITK * B_SZ * DDATA * 4);
  float*  pp   = (float*)carve((size_t)GZCH * B_SZ * 128 * 4);   // 8.4 MB
  float*  ps   = (float*)carve((size_t)GZCH * B_SZ * 128 * 4);   // 8.4 MB
  unsigned int* cnt  = (unsigned int*)carve(256);
  unsigned int* list = (unsigned int*)carve((size_t)B_SZ * 128 * 4);

  k_init  <<<16, 256, 0, stream>>>(be1, cv, cnt);
  k_xcast <<<1536, 256, 0, stream>>>(x, xb);
  k_t1c   <<<dim3(12, 128), 256, 0, stream>>>(We1, bd1, W1T, cv);
  k_t2    <<<dim3(68, 12),  256, 0, stream>>>(Wd1, Wd0, bd1, B2T);
  // gate: fp32 flag pass + exact fp64 fix-up
  k_gatep3<<<dim3(64, GZCH), 256, 0, stream>>>(x, We0, bd0, pp, ps);
  k_gater2<<<1024, 256, 0, stream>>>(pp, ps, be0, A2, cnt, list);
  k_fix   <<<96, 256, 0, stream>>>(cnt, list, x, We0, be0, bd0, A2);
  // GEMM1: pre/acts1 -> A2[:, 0..4095]   (M=2048, N=4096, K=768)
  k_gemm<128, 128, 1><<<dim3(32, 16, 1), 256, 0, stream>>>(xb, W1T, DDATA, DDATA,
                                                           nullptr, A2, cv);
  // GEMM2 split-K: part[z] = A2 @ B2 over K-chunk z   (M=2048, N=768, K=4352)
  k_gemm<64, 128, 2><<<dim3(6, 32, SPLITK), 256, 0, stream>>>(A2, B2T, KA2, KC2,
                                                              part, nullptr, nullptr);
  k_reduce<<<1536, 256, 0, stream>>>(part, bd0, out);
}